// Round 14
// baseline (54.059 us; speedup 1.0000x reference)
//
#include <hip/hip_runtime.h>

#define KK 16
#define SS 4
#define EE 64
#define BB 2
#define DT_CONST 0.005f

typedef float f32x4 __attribute__((ext_vector_type(4)));
typedef short bf16x8 __attribute__((ext_vector_type(8)));

// ws float layout: [0, 139264) transposed gram partials: slot (b*136+p)*512 + tile
// [139264, +4096) wk bf16 ushorts: hi[2][64][32] then lo[2][64][32]
#define WS_WK_F 139264

// ---------------- kernel A: sliding-correlation Gram, quarter-split lanes ----------------
// grid 1024 (4 rows each); block 256 = 4 rows x (16 lags x 4 quarters).
// Window for C(d1): u in [d1, d1+64]; quarter q covers 16 (17 for q=3) elems.
__global__ void __launch_bounds__(256, 4) kA_gram(const float* __restrict__ events,
                                                  float* __restrict__ ws) {
    __shared__ float xs[4][97];     // xpad: [0..7]=0, [8..71]=x, [72..96]=0
    __shared__ float S1L[4][16];
    __shared__ float part[4][136];
    const int tid = threadIdx.x;

    if (tid < 64) {                 // 4 rows = 1 KB contiguous, coalesced
        const float4* src = reinterpret_cast<const float4*>(
            events + (size_t)blockIdx.x * 256);
        float4 v = src[tid];
        int r = tid >> 4, c0 = ((tid & 15) << 2) + 8;
        xs[r][c0] = v.x; xs[r][c0+1] = v.y; xs[r][c0+2] = v.z; xs[r][c0+3] = v.w;
    }
    if (tid < 132) {                // zero pads: 4 rows x 33
        int rr = tid / 33, k = tid % 33;
        xs[rr][(k < 8) ? k : (k + 64)] = 0.f;
    }
    __syncthreads();

    const int r   = tid >> 6;       // 0..3
    const int l   = tid & 63;
    const int lag = l >> 2;         // 0..15 (uniform within 4-lane group)
    const int q   = l & 3;
    const int off = q << 4;
    const float inv65 = 1.f / 65.f;

    // S1[d=lag] = sum_{u=0}^{64} xpad[d+u], quarter-split
    {
        float s = 0.f;
#pragma unroll
        for (int j = 0; j < 16; ++j) s += xs[r][lag + off + j];
        if (q == 3) s += xs[r][lag + 64];
        s += __shfl_xor(s, 1, 64);
        s += __shfl_xor(s, 2, 64);
        if (q == 0) S1L[r][lag] = s;
    }
    __syncthreads();

    // C(d1) = sum_{u=d1}^{d1+64} xs[u]*xs[u+lag]; slide d1 = 0..15
    {
        float C = 0.f;
#pragma unroll
        for (int j = 0; j < 16; ++j) C += xs[r][off + j] * xs[r][off + j + lag];
        if (q == 3) C += xs[r][64] * xs[r][64 + lag];
        {
            float Ct = C + __shfl_xor(C, 1, 64);
            Ct += __shfl_xor(Ct, 2, 64);
            if (q == 0) part[r][lag] = Ct - S1L[r][0] * S1L[r][lag] * inv65;
        }
        const int len = 16 + (q == 3 ? 1 : 0);
#pragma unroll
        for (int d1 = 1; d1 <= 15; ++d1) {
            const int add = d1 - 1 + off + len;   // new top of this quarter
            const int rem = d1 - 1 + off;         // dropped bottom
            C += xs[r][add] * xs[r][add + lag] - xs[r][rem] * xs[r][rem + lag];
            if (lag + d1 <= 15) {                 // uniform within 4-lane group
                float Ct = C + __shfl_xor(C, 1, 64);
                Ct += __shfl_xor(Ct, 2, 64);
                if (q == 0) {
                    int p = 16 * d1 - ((d1 * (d1 - 1)) >> 1) + lag;
                    part[r][p] = Ct - S1L[r][d1] * S1L[r][d1 + lag] * inv65;
                }
            }
        }
    }
    __syncthreads();

    if (tid < 136) {
        float g = part[0][tid] + part[1][tid] + part[2][tid] + part[3][tid];
        ws[((size_t)((blockIdx.x >> 9) * 136 + tid)) * 512 + (blockIdx.x & 511)] = g;
    }
}

// ---------------- kernel M: reduce partials (512 tiles), fv, MLP, softmax, wk bf16 ----
__global__ void __launch_bounds__(256, 1) kM_mlp(const float* __restrict__ tc,
        const float* __restrict__ tk, const float* __restrict__ w1,
        const float* __restrict__ b1, const float* __restrict__ w2,
        const float* __restrict__ b2, float* __restrict__ ws) {
    __shared__ float Gf[2 * 256];
    __shared__ float combL[SS * EE * KK];
    __shared__ float fvL[BB * SS];
    __shared__ float attnL[BB][SS];
    const int tid = threadIdx.x;

    for (int v = tid; v < 272; v += 256) {
        int b = (v >= 136) ? 1 : 0;
        int p = v - b * 136;
        int pp = p, d1 = 0;
        while (pp >= KK - d1) { pp -= KK - d1; ++d1; }
        int d2 = d1 + pp;
        const float4* rp = reinterpret_cast<const float4*>(ws + (size_t)v * 512);
        float acc = 0.f;
#pragma unroll 16
        for (int i = 0; i < 128; ++i) { float4 qv = rp[i]; acc += (qv.x + qv.y) + (qv.z + qv.w); }
        Gf[b * 256 + d1 * KK + d2] = acc;
        Gf[b * 256 + d2 * KK + d1] = acc;
    }
    {
        int s = tid >> 6;
        float inv = DT_CONST / tc[s];
        float dk[KK]; float dsum = 0.f;
#pragma unroll
        for (int j = 0; j < KK; ++j) { dk[j] = expf(-(float)j * inv); dsum += dk[j]; }
        float rn = 1.f / dsum;
#pragma unroll
        for (int i = 0; i < 4; ++i) {
            float4 v = reinterpret_cast<const float4*>(tk + tid * KK)[i];
            combL[tid * KK + 4*i + 0] = dk[4*i + 0] * rn * v.x;
            combL[tid * KK + 4*i + 1] = dk[4*i + 1] * rn * v.y;
            combL[tid * KK + 4*i + 2] = dk[4*i + 2] * rn * v.z;
            combL[tid * KK + 4*i + 3] = dk[4*i + 3] * rn * v.w;
        }
    }
    __syncthreads();
    {
        float cvec[KK];
#pragma unroll
        for (int i = 0; i < 4; ++i) {
            float4 v = reinterpret_cast<const float4*>(combL + tid * KK)[i];
            cvec[4*i] = v.x; cvec[4*i+1] = v.y; cvec[4*i+2] = v.z; cvec[4*i+3] = v.w;
        }
        float acc0 = 0.f, acc1 = 0.f;
#pragma unroll
        for (int d1 = 0; d1 < KK; ++d1) {
            float cd1 = cvec[d1];
            float t0 = 0.5f * Gf[d1 * KK + d1] * cd1;
            float t1 = 0.5f * Gf[256 + d1 * KK + d1] * cd1;
#pragma unroll
            for (int d2 = d1 + 1; d2 < KK; ++d2) {
                t0 += Gf[d1 * KK + d2] * cvec[d2];
                t1 += Gf[256 + d1 * KK + d2] * cvec[d2];
            }
            acc0 += 2.f * cd1 * t0;
            acc1 += 2.f * cd1 * t1;
        }
#pragma unroll
        for (int sft = 1; sft < 64; sft <<= 1) {
            acc0 += __shfl_xor(acc0, sft, 64);
            acc1 += __shfl_xor(acc1, sft, 64);
        }
        if ((tid & 63) == 0) {
            const float scale = 1.f / 8388608.f;   // 1/(E*(Tp-1)*Cf)
            fvL[(tid >> 6)]     = acc0 * scale;
            fvL[4 + (tid >> 6)] = acc1 * scale;
        }
    }
    __syncthreads();
    if (tid < 2) {
        int b = tid;
        float h[8];
#pragma unroll
        for (int i = 0; i < 8; ++i) {
            float a = b1[i];
#pragma unroll
            for (int s = 0; s < SS; ++s) a += fvL[b * SS + s] * w1[i * SS + s];
            h[i] = a > 0.f ? a : 0.f;
        }
        float lg[SS]; float mx = -1e30f;
#pragma unroll
        for (int s = 0; s < SS; ++s) {
            float a = b2[s];
#pragma unroll
            for (int i = 0; i < 8; ++i) a += h[i] * w2[s * 8 + i];
            lg[s] = a; mx = fmaxf(mx, a);
        }
        float se = 0.f;
#pragma unroll
        for (int s = 0; s < SS; ++s) { lg[s] = expf(lg[s] - mx); se += lg[s]; }
#pragma unroll
        for (int s = 0; s < SS; ++s) attnL[b][s] = lg[s] / se;
    }
    __syncthreads();
    {
        unsigned short* wkp = reinterpret_cast<unsigned short*>(ws + WS_WK_F);
#pragma unroll
        for (int j = 0; j < 8; ++j) {
            int o = tid * 8 + j;                    // [0,2048)
            int b = o >> 10, e = (o >> 4) & 63, k = o & 15;
            float a = 0.f;
#pragma unroll
            for (int s = 0; s < SS; ++s)
                a += attnL[b][s] * combL[(s * EE + e) * KK + k];
            unsigned int bits = __float_as_uint(a);
            unsigned short hh = (unsigned short)(bits >> 16);
            float hf = __uint_as_float(((unsigned int)hh) << 16);
            unsigned short ll = (unsigned short)(__float_as_uint(a - hf) >> 16);
            int base = b * 2048 + e * 32 + k;
            wkp[base]          = hh;   wkp[base + 16]        = 0;
            wkp[4096 + base]   = ll;   wkp[4096 + base + 16] = 0;
        }
    }
}

// ---------------- kernel C: MFMA conv, 2 cf rows/block, direct stores (R12 verbatim) ----
__global__ void __launch_bounds__(256, 8) kC_conv(const float* __restrict__ events,
                                                  const float* __restrict__ ws,
                                                  float* __restrict__ out) {
    __shared__ float xs[2][97];
    __shared__ __align__(16) unsigned short Bh[80 * 24 + 16];
    __shared__ __align__(16) unsigned short Bl[80 * 24 + 16];
    const int tid = threadIdx.x;
    const int bid = blockIdx.x;
    const int b   = bid >> 10;
    const int cf0 = (bid & 1023) << 1;
    const int w   = tid >> 6, l = tid & 63, llo = l & 15, lhi = l >> 4;

    for (int idx = tid; idx < 80 * 24 + 16; idx += 256) { Bh[idx] = 0; Bl[idx] = 0; }

    const unsigned short* wkp = reinterpret_cast<const unsigned short*>(ws + WS_WK_F);
    bf16x8 Ah = *reinterpret_cast<const bf16x8*>(wkp + b * 2048 + (w * 16 + llo) * 32 + 8 * lhi);
    bf16x8 Al = *reinterpret_cast<const bf16x8*>(wkp + 4096 + b * 2048 + (w * 16 + llo) * 32 + 8 * lhi);

    if (tid < 32) {
        float4 v = reinterpret_cast<const float4*>(
            events + ((size_t)b * 2048 + cf0) * 64)[tid];
        int rr = tid >> 4, c0 = ((tid & 15) << 2) + 8;
        xs[rr][c0] = v.x; xs[rr][c0+1] = v.y; xs[rr][c0+2] = v.z; xs[rr][c0+3] = v.w;
    }
    for (int idx = tid; idx < 66; idx += 256) {
        int rr = idx / 33, k = idx % 33;
        xs[rr][(k < 8) ? k : (k + 64)] = 0.f;
    }
    __syncthreads();

#pragma unroll 1
    for (int rr = 0; rr < 2; ++rr) {
#pragma unroll
        for (int q = 0; q < 5; ++q) {
            int idx = tid + q * 256;               // [0,1280)
            int t = idx >> 4, k = idx & 15;
            float x = xs[rr][t + k];
            unsigned int bits = __float_as_uint(x);
            unsigned short hh = (unsigned short)(bits >> 16);
            float hf = __uint_as_float(((unsigned int)hh) << 16);
            unsigned short ll = (unsigned short)(__float_as_uint(x - hf) >> 16);
            Bh[t * 24 + k] = hh;
            Bl[t * 24 + k] = ll;
        }
        __syncthreads();

        const size_t obase = ((size_t)(b * 64 + w * 16 + lhi * 4) * 2048 + (cf0 + rr)) * 65;
#pragma unroll
        for (int nt = 0; nt < 5; ++nt) {
            bf16x8 Xh = *reinterpret_cast<const bf16x8*>(Bh + (nt * 16 + llo) * 24 + 8 * lhi);
            bf16x8 Xl = *reinterpret_cast<const bf16x8*>(Bl + (nt * 16 + llo) * 24 + 8 * lhi);
            f32x4 acc = {0.f, 0.f, 0.f, 0.f};
            acc = __builtin_amdgcn_mfma_f32_16x16x32_bf16(Al, Xh, acc, 0, 0, 0);
            acc = __builtin_amdgcn_mfma_f32_16x16x32_bf16(Ah, Xl, acc, 0, 0, 0);
            acc = __builtin_amdgcn_mfma_f32_16x16x32_bf16(Ah, Xh, acc, 0, 0, 0);
            const int t0 = nt * 16 + llo;
            if (t0 < 65) {
#pragma unroll
                for (int i = 0; i < 4; ++i)
                    out[obase + (size_t)i * (2048 * 65) + t0] = acc[i];
            }
        }
        __syncthreads();
    }
}

extern "C" void kernel_launch(void* const* d_in, const int* in_sizes, int n_in,
                              void* d_out, int out_size, void* d_ws, size_t ws_size,
                              hipStream_t stream) {
    const float* events = (const float*)d_in[0];
    const float* tc     = (const float*)d_in[1];
    const float* tk     = (const float*)d_in[2];
    const float* w1     = (const float*)d_in[3];
    const float* b1     = (const float*)d_in[4];
    const float* w2     = (const float*)d_in[5];
    const float* b2     = (const float*)d_in[6];
    float* out = (float*)d_out;
    float* ws  = (float*)d_ws;

    hipLaunchKernelGGL(kA_gram, dim3(1024), dim3(256), 0, stream, events, ws);
    hipLaunchKernelGGL(kM_mlp,  dim3(1),    dim3(256), 0, stream, tc, tk, w1, b1, w2, b2, ws);
    hipLaunchKernelGGL(kC_conv, dim3(2048), dim3(256), 0, stream, events, ws, out);
}

// Round 15
// 37.251 us; speedup vs baseline: 1.4512x; 1.4512x over previous
//
#include <hip/hip_runtime.h>

#define KK 16
#define SS 4
#define EE 64
#define BB 2
#define DT_CONST 0.005f

typedef float f32x4 __attribute__((ext_vector_type(4)));
typedef short bf16x8 __attribute__((ext_vector_type(8)));

// ws: transposed gram partials only: slot (b*136+p)*128 + tile

// ---------------- kernel A: sliding-correlation Gram, half-split lanes (R12 verbatim) ----
__global__ void __launch_bounds__(512, 1) kA_gram(const float* __restrict__ events,
                                                  float* __restrict__ ws) {
    __shared__ float xs[16][97];    // xpad: [0..7]=0, [8..71]=x, [72..96]=0
    __shared__ float S1L[16][16];
    __shared__ float part[16][136];
    const int tid = threadIdx.x;

    if (tid < 256) {
        const float4* src = reinterpret_cast<const float4*>(
            events + (size_t)blockIdx.x * 1024);
        float4 v = src[tid];
        int r = tid >> 4, c0 = ((tid & 15) << 2) + 8;
        xs[r][c0] = v.x; xs[r][c0+1] = v.y; xs[r][c0+2] = v.z; xs[r][c0+3] = v.w;
    }
    for (int idx = tid; idx < 16 * 33; idx += 512) {
        int rr = idx / 33, k = idx % 33;
        xs[rr][(k < 8) ? k : (k + 64)] = 0.f;
    }
    __syncthreads();

    const int r   = tid >> 5;
    const int c   = tid & 31;
    const int lag = c >> 1;
    const int h   = c & 1;
    const int off = h * 33;
    const float inv65 = 1.f / 65.f;

    {
        float s = 0.f;
#pragma unroll
        for (int j = 0; j < 32; ++j) s += xs[r][lag + off + j];
        if (!h) s += xs[r][lag + 32];
        s += __shfl_xor(s, 1, 64);
        if (!h) S1L[r][lag] = s;
    }
    __syncthreads();

    {
        float C = 0.f;
#pragma unroll
        for (int j = 0; j < 32; ++j) C += xs[r][off + j] * xs[r][off + j + lag];
        if (!h) C += xs[r][32] * xs[r][32 + lag];
        {
            float Ct = C + __shfl_xor(C, 1, 64);
            if (!h) part[r][lag] = Ct - S1L[r][0] * S1L[r][lag] * inv65;
        }
#pragma unroll
        for (int d1 = 1; d1 <= 15; ++d1) {
            const int add = d1 + off + 32 - h;
            const int rem = d1 - 1 + off;
            C += xs[r][add] * xs[r][add + lag] - xs[r][rem] * xs[r][rem + lag];
            if (lag + d1 <= 15) {
                float Ct = C + __shfl_xor(C, 1, 64);
                if (!h) {
                    int p = 16 * d1 - ((d1 * (d1 - 1)) >> 1) + lag;
                    part[r][p] = Ct - S1L[r][d1] * S1L[r][d1 + lag] * inv65;
                }
            }
        }
    }
    __syncthreads();

    if (tid < 136) {
        float g = 0.f;
#pragma unroll
        for (int rr = 0; rr < 16; ++rr) g += part[rr][tid];
        ws[((size_t)((blockIdx.x >> 7) * 136 + tid)) * 128 + (blockIdx.x & 127)] = g;
    }
}

// ---------------- kernel B5: redundant prologue + pipelined staged MFMA conv ----------
// grid 512 = b(2) x 256 groups of 8 cf; block 256 = 4 waves (wave = 16-e tile).
// Pipeline per cf: copyout(cf-1) || MFMA(cf) || build B(cf+1); ONE barrier per cf.
__global__ void __launch_bounds__(256, 2) kB5_main(
        const float* __restrict__ events, const float* __restrict__ tc,
        const float* __restrict__ tk, const float* __restrict__ w1,
        const float* __restrict__ b1, const float* __restrict__ w2,
        const float* __restrict__ b2, const float* __restrict__ ws,
        float* __restrict__ out) {
    __shared__ float stage[2][4352];                 // conv stage [64][68]; prologue overlay
    __shared__ float xs[8 * 97];                     // xpad rows
    __shared__ __align__(16) unsigned short wkh[64 * 32];  // wk hi, K-padded (zeros)
    __shared__ __align__(16) unsigned short wkl[64 * 32];  // wk lo
    __shared__ __align__(16) unsigned short Bh[2][1936];   // im2col^T hi [t][k], stride 24
    __shared__ __align__(16) unsigned short Bl[2][1936];
    float* Gf    = stage[0];                         // [2][16][16] = 512
    float* fvL   = stage[0] + 512;                   // [2][4]
    float* combL = stage[1];                         // [4][64][16] = 4096
    const int tid = threadIdx.x;
    const int bid = blockIdx.x;
    const int b   = bid >> 8;
    const int w   = tid >> 6, l = tid & 63, llo = l & 15, lhi = l >> 4;

    // --- prologue phase 1: zero/load + gram reduce + combined ---
    for (int idx = tid; idx < 2 * 1936; idx += 256) { Bh[0][idx] = 0; Bl[0][idx] = 0; }
    for (int idx = tid; idx < 8 * 33; idx += 256) {
        int rr = idx / 33, k = idx % 33;
        xs[rr * 97 + ((k < 8) ? k : (k + 64))] = 0.f;
    }
    if (tid < 128) {
        float4 v = reinterpret_cast<const float4*>(events + (size_t)bid * 512)[tid];
        int rr = tid >> 4, c0 = ((tid & 15) << 2) + 8;
        xs[rr * 97 + c0] = v.x; xs[rr * 97 + c0 + 1] = v.y;
        xs[rr * 97 + c0 + 2] = v.z; xs[rr * 97 + c0 + 3] = v.w;
    }
    for (int v = tid; v < 272; v += 256) {
        int b2i = (v >= 136) ? 1 : 0;
        int p  = v - b2i * 136;
        int pp = p, d1 = 0;
        while (pp >= KK - d1) { pp -= KK - d1; ++d1; }
        int d2 = d1 + pp;
        const float4* rp = reinterpret_cast<const float4*>(ws + (size_t)v * 128);
        float acc = 0.f;
#pragma unroll
        for (int i = 0; i < 32; ++i) { float4 q = rp[i]; acc += (q.x + q.y) + (q.z + q.w); }
        Gf[(b2i * KK + d1) * KK + d2] = acc;
        Gf[(b2i * KK + d2) * KK + d1] = acc;
    }
    {
        int s = tid >> 6;
        float inv = DT_CONST / tc[s];
        float dk[KK]; float dsum = 0.f;
#pragma unroll
        for (int j = 0; j < KK; ++j) { dk[j] = expf(-(float)j * inv); dsum += dk[j]; }
        float rn = 1.f / dsum;
#pragma unroll
        for (int i = 0; i < 4; ++i) {
            float4 v = reinterpret_cast<const float4*>(tk + tid * KK)[i];
            combL[tid * KK + 4*i + 0] = dk[4*i + 0] * rn * v.x;
            combL[tid * KK + 4*i + 1] = dk[4*i + 1] * rn * v.y;
            combL[tid * KK + 4*i + 2] = dk[4*i + 2] * rn * v.z;
            combL[tid * KK + 4*i + 3] = dk[4*i + 3] * rn * v.w;
        }
    }
    __syncthreads();

    // --- prologue phase 2: quadratic forms -> fv ---
    {
        float cvec[KK];
#pragma unroll
        for (int i = 0; i < 4; ++i) {
            float4 v = reinterpret_cast<const float4*>(combL + tid * KK)[i];
            cvec[4*i] = v.x; cvec[4*i+1] = v.y; cvec[4*i+2] = v.z; cvec[4*i+3] = v.w;
        }
        float acc0 = 0.f, acc1 = 0.f;
#pragma unroll
        for (int d1 = 0; d1 < KK; ++d1) {
            float cd1 = cvec[d1];
            float t0 = 0.5f * Gf[d1 * KK + d1] * cd1;
            float t1 = 0.5f * Gf[256 + d1 * KK + d1] * cd1;
#pragma unroll
            for (int d2 = d1 + 1; d2 < KK; ++d2) {
                t0 += Gf[d1 * KK + d2] * cvec[d2];
                t1 += Gf[256 + d1 * KK + d2] * cvec[d2];
            }
            acc0 += 2.f * cd1 * t0;
            acc1 += 2.f * cd1 * t1;
        }
#pragma unroll
        for (int sft = 1; sft < 64; sft <<= 1) {
            acc0 += __shfl_xor(acc0, sft, 64);
            acc1 += __shfl_xor(acc1, sft, 64);
        }
        if ((tid & 63) == 0) {
            const float scale = 1.f / 8388608.f;     // 1/(E*(Tp-1)*Cf)
            fvL[(tid >> 6)]     = acc0 * scale;
            fvL[4 + (tid >> 6)] = acc1 * scale;
        }
    }
    __syncthreads();

    // --- prologue phase 3: MLP+softmax (own b) -> wk bf16 hi/lo; build B[0] ---
    {
        float fv[SS];
#pragma unroll
        for (int s = 0; s < SS; ++s) fv[s] = fvL[b * SS + s];
        float h[8];
#pragma unroll
        for (int i = 0; i < 8; ++i) {
            float a = b1[i];
#pragma unroll
            for (int s = 0; s < SS; ++s) a += fv[s] * w1[i * SS + s];
            h[i] = a > 0.f ? a : 0.f;
        }
        float lg[SS]; float mx = -1e30f;
#pragma unroll
        for (int s = 0; s < SS; ++s) {
            float a = b2[s];
#pragma unroll
            for (int i = 0; i < 8; ++i) a += h[i] * w2[s * 8 + i];
            lg[s] = a; mx = fmaxf(mx, a);
        }
        float se = 0.f;
#pragma unroll
        for (int s = 0; s < SS; ++s) { lg[s] = expf(lg[s] - mx); se += lg[s]; }
        float attn[SS];
#pragma unroll
        for (int s = 0; s < SS; ++s) attn[s] = lg[s] / se;
#pragma unroll
        for (int j = 0; j < 4; ++j) {
            int idx = tid * 4 + j;                   // [0,1024)
            int e = idx >> 4, k2 = idx & 15;
            float a = 0.f;
#pragma unroll
            for (int s = 0; s < SS; ++s)
                a += attn[s] * combL[(s * EE + e) * KK + k2];
            unsigned int bits = __float_as_uint(a);
            unsigned short hh = (unsigned short)(bits >> 16);
            float hf = __uint_as_float(((unsigned int)hh) << 16);
            unsigned short ll = (unsigned short)(__float_as_uint(a - hf) >> 16);
            wkh[e * 32 + k2] = hh;      wkl[e * 32 + k2] = ll;
            wkh[e * 32 + 16 + k2] = 0;  wkl[e * 32 + 16 + k2] = 0;
        }
    }
    // build B[0] from xs row 0
#pragma unroll
    for (int q = 0; q < 5; ++q) {
        int idx = tid + q * 256;                     // [0,1280)
        int t = idx >> 4, k = idx & 15;
        float x = xs[t + k];
        unsigned int bits = __float_as_uint(x);
        unsigned short hh = (unsigned short)(bits >> 16);
        float hf = __uint_as_float(((unsigned int)hh) << 16);
        unsigned short ll = (unsigned short)(__float_as_uint(x - hf) >> 16);
        Bh[0][t * 24 + k] = hh;
        Bl[0][t * 24 + k] = ll;
    }
    __syncthreads();

    // --- pipelined conv: one barrier per cf ---
    bf16x8 Ah = *reinterpret_cast<const bf16x8*>(&wkh[(w * 16 + llo) * 32 + 8 * lhi]);
    bf16x8 Al = *reinterpret_cast<const bf16x8*>(&wkl[(w * 16 + llo) * 32 + 8 * lhi]);
    const size_t obase0 = ((size_t)b * 64 * 2048 + (size_t)(bid & 255) * 8) * 65;

#pragma unroll 1
    for (int cf = 0; cf < 8; ++cf) {
        const int cur = cf & 1;
        // MFMA from B[cur] -> stage[cur]
#pragma unroll
        for (int nt = 0; nt < 5; ++nt) {
            bf16x8 Xh = *reinterpret_cast<const bf16x8*>(&Bh[cur][(nt * 16 + llo) * 24 + 8 * lhi]);
            bf16x8 Xl = *reinterpret_cast<const bf16x8*>(&Bl[cur][(nt * 16 + llo) * 24 + 8 * lhi]);
            f32x4 acc = {0.f, 0.f, 0.f, 0.f};
            acc = __builtin_amdgcn_mfma_f32_16x16x32_bf16(Al, Xh, acc, 0, 0, 0);
            acc = __builtin_amdgcn_mfma_f32_16x16x32_bf16(Ah, Xl, acc, 0, 0, 0);
            acc = __builtin_amdgcn_mfma_f32_16x16x32_bf16(Ah, Xh, acc, 0, 0, 0);
            if (nt < 4 || llo < 4) {
#pragma unroll
                for (int i = 0; i < 4; ++i)
                    stage[cur][(w * 16 + lhi * 4 + i) * 68 + nt * 16 + llo] = acc[i];
            }
        }
        // build B[cur^1] for cf+1
        if (cf < 7) {
            const float* xrow = xs + (cf + 1) * 97;
#pragma unroll
            for (int q = 0; q < 5; ++q) {
                int idx = tid + q * 256;
                int t = idx >> 4, k = idx & 15;
                float x = xrow[t + k];
                unsigned int bits = __float_as_uint(x);
                unsigned short hh = (unsigned short)(bits >> 16);
                float hf = __uint_as_float(((unsigned int)hh) << 16);
                unsigned short ll = (unsigned short)(__float_as_uint(x - hf) >> 16);
                Bh[cur ^ 1][t * 24 + k] = hh;
                Bl[cur ^ 1][t * 24 + k] = ll;
            }
        }
        // copyout stage[cur^1] = result of cf-1
        if (cf > 0) {
            const float* sg = stage[cur ^ 1];
            const size_t ob = obase0 + (size_t)(cf - 1) * 65;
            int q = tid >> 6, tloc = tid & 63;
#pragma unroll
            for (int kk = 0; kk < 16; ++kk) {
                int e = q * 16 + kk;
                out[ob + (size_t)e * 133120 + tloc] = sg[e * 68 + tloc];
            }
            if (tid < 64) out[ob + (size_t)tid * 133120 + 64] = sg[tid * 68 + 64];
        }
        __syncthreads();
    }
    // drain: copyout cf=7 from stage[1]
    {
        const float* sg = stage[1];
        const size_t ob = obase0 + (size_t)7 * 65;
        int q = tid >> 6, tloc = tid & 63;
#pragma unroll
        for (int kk = 0; kk < 16; ++kk) {
            int e = q * 16 + kk;
            out[ob + (size_t)e * 133120 + tloc] = sg[e * 68 + tloc];
        }
        if (tid < 64) out[ob + (size_t)tid * 133120 + 64] = sg[tid * 68 + 64];
    }
}

extern "C" void kernel_launch(void* const* d_in, const int* in_sizes, int n_in,
                              void* d_out, int out_size, void* d_ws, size_t ws_size,
                              hipStream_t stream) {
    const float* events = (const float*)d_in[0];
    const float* tc     = (const float*)d_in[1];
    const float* tk     = (const float*)d_in[2];
    const float* w1     = (const float*)d_in[3];
    const float* b1     = (const float*)d_in[4];
    const float* w2     = (const float*)d_in[5];
    const float* b2     = (const float*)d_in[6];
    float* out = (float*)d_out;
    float* ws  = (float*)d_ws;

    hipLaunchKernelGGL(kA_gram,  dim3(256), dim3(512), 0, stream, events, ws);
    hipLaunchKernelGGL(kB5_main, dim3(512), dim3(256), 0, stream,
                       events, tc, tk, w1, b1, w2, b2, ws, out);
}